// Round 1
// baseline (652.997 us; speedup 1.0000x reference)
//
#include <hip/hip_runtime.h>
#include <math.h>

// LMNN-style loss: outputs (2048,512,128) f32, label_inds (2048,511) i32 -> scalar.
// HBM-read-bound in principle (512 MiB read once; floor ~85us @6.3TB/s).
// R4: replace the 5-deep __shfl_xor butterfly per point (lowers to ~25 instrs +
// 4 dependent ds_bpermute chains per point-pair; issue/latency-bound at ~1.7TB/s)
// with an LDS transpose-reduce:
//   phase 1: each wave writes per-lane partial d2 for a private 16-point tile
//            into LDS (1 conflict-free ds_write_b32 per point, no shuffles)
//   phase 2: 4 lanes per point read the 32 partials back as two aligned
//            ds_read_b128 (stride 36 floats -> <=2-way bank aliasing = free)
//            and finish with only 2 shuffles (xor16, xor32).
// ~3x fewer instructions per byte; dependent bpermute chains eliminated.

constexpr int NSEG = 2048;
constexpr int PPS  = 512;   // points per segment incl. center
constexpr int NPTS = 511;   // pts excluding center
constexpr int DIM  = 128;
constexpr int BLK  = 256;   // 4 waves; 2048 blocks -> 8 blocks/CU -> 32 waves/CU
constexpr int TP   = 16;    // points per wave-tile
constexpr int PSTR = 36;    // partial-row stride (floats): 16B-aligned, low-conflict

typedef float f4_t __attribute__((ext_vector_type(4)));

__global__ __launch_bounds__(BLK) void lmnn_kernel(
    const float* __restrict__ outputs,
    const int*  __restrict__ labels,
    float* __restrict__ out)
{
    const int s    = blockIdx.x;
    const int tid  = threadIdx.x;
    const int lane = tid & 63;
    const int wave = tid >> 6;   // 0..3
    const int half = lane >> 5;  // which point of the pair this lane serves
    const int sl   = lane & 31;  // sub-lane within the 32-lane half

    __shared__ float part[4][TP][PSTR];   // wave-private partial tiles (~9 KB)
    __shared__ float d2s[NPTS];
    __shared__ unsigned char same_s[NPTS];
    __shared__ float red[8];

    const float* seg  = outputs + (size_t)s * (PPS * DIM);
    const f4_t*  seg4 = (const f4_t*)seg;
    const int*   lab  = labels + (size_t)s * NPTS;

    // same-label flags (lab[0] is scalar-broadcast)
    const int lab0 = lab[0];
    for (int j = tid; j < NPTS; j += BLK)
        same_s[j] = (lab[j] == lab0) ? 1 : 0;

    // this lane's center chunk: floats [4*sl .. 4*sl+3]
    const f4_t c = seg4[sl];

    // d2 for all points; each wave owns a private 16-point tile per iter.
    for (int jb = wave * TP; jb < NPTS; jb += 4 * TP) {
        // ---- phase 1: per-lane partials -> part[wave][t][sl] ----
        #pragma unroll
        for (int b = 0; b < 2; ++b) {         // two 4-deep load batches (keeps VGPR <= ~64)
            f4_t p[4];
            #pragma unroll
            for (int u = 0; u < 4; ++u) {
                const int t = 8 * b + 2 * u + half;
                const int j = jb + t;
                const f4_t* src = seg4 + (size_t)(j + 1) * (DIM / 4) + sl;
                // guard only trips at j==511 (last tile); clamp to center row
                // -> partial becomes 0 there, and the d2s write is guarded below.
                const f4_t* safe = (j < NPTS) ? src : (seg4 + sl);
                p[u] = __builtin_nontemporal_load(safe);
            }
            #pragma unroll
            for (int u = 0; u < 4; ++u) {
                const int t = 8 * b + 2 * u + half;
                f4_t d = p[u] - c;
                part[wave][t][sl] = d.x * d.x + d.y * d.y + d.z * d.z + d.w * d.w;
            }
        }
        asm volatile("" ::: "memory");  // keep phase-2 reads after phase-1 writes

        // ---- phase 2: column-reduce; 4 lanes per point ----
        const int pt = lane & 15;       // point within tile
        const int g  = lane >> 4;       // 8-float group of the 32 partials
        const float* pr = &part[wave][pt][0] + g * 8;
        const f4_t a0 = *(const f4_t*)pr;        // aligned: PSTR=36, g*8*4B = 32B
        const f4_t a1 = *(const f4_t*)(pr + 4);
        float v = ((a0.x + a0.y) + (a0.z + a0.w)) + ((a1.x + a1.y) + (a1.z + a1.w));
        v += __shfl_xor(v, 16, 64);     // combine groups across bit 4
        v += __shfl_xor(v, 32, 64);     // combine groups across bit 5
        const int j = jb + pt;
        if (g == 0 && j < NPTS) d2s[j] = v;
        asm volatile("" ::: "memory");  // keep next iter's writes after these reads
    }
    __syncthreads();

    // pull = min d2 over same-label points (j=0 always same -> well-defined)
    float m = INFINITY;
    for (int j = tid; j < NPTS; j += BLK)
        if (same_s[j]) m = fminf(m, d2s[j]);
    #pragma unroll
    for (int o = 32; o > 0; o >>= 1)
        m = fminf(m, __shfl_xor(m, o, 64));
    if (lane == 0) red[wave] = m;
    __syncthreads();

    const float pull   = fminf(fminf(red[0], red[1]), fminf(red[2], red[3]));
    const float margin = 1.0f + pull;

    // push = sum over different-label points of max(margin - d2, 0)
    float p = 0.0f;
    for (int j = tid; j < NPTS; j += BLK)
        if (!same_s[j]) p += fmaxf(margin - d2s[j], 0.0f);
    #pragma unroll
    for (int o = 32; o > 0; o >>= 1)
        p += __shfl_xor(p, o, 64);
    if (lane == 0) red[4 + wave] = p;  // distinct slots from red[0..3]
    __syncthreads();

    if (tid == 0) {
        const float total = pull + red[4] + red[5] + red[6] + red[7];
        atomicAdd(out, total * (1.0f / (float)(NSEG * PPS)));
    }
}

extern "C" void kernel_launch(void* const* d_in, const int* in_sizes, int n_in,
                              void* d_out, int out_size, void* d_ws, size_t ws_size,
                              hipStream_t stream) {
    const float* outputs = (const float*)d_in[0];
    const int*   labels  = (const int*)d_in[1];
    float* out = (float*)d_out;

    // d_out is re-poisoned to 0xAA before every timed launch -> zero it on-stream.
    (void)hipMemsetAsync(out, 0, sizeof(float) * out_size, stream);
    lmnn_kernel<<<NSEG, BLK, 0, stream>>>(outputs, labels, out);
}